// Round 17
// baseline (47.569 us; speedup 1.0000x reference)
//
#include <hip/hip_runtime.h>
#include <stdint.h>

// ---------------------------------------------------------------------------
// AdditiveAttention (Bahdanau) + gumbel-softmax(tau=0.01), channel 0.
//
// out[b,i,j] = (mask==1) ? 1.0 : sigmoid((d + g0 - g1)*100),
//   d = sum_h tanh(q+k)*(w0-w1);  g bit-exact jax threefry (verified R3-R16).
//
// R17: OCCUPANCY restructure. R15/R16 evidence: attn(1x)=35us wall vs
// ~10-13us overlapped issue floor; 512 blocks = 2 blocks/CU = 25% occ cap
// (grid-limited), LDS 51.2KB. Poor 2x-work scaling (1.46x) = latency-bound.
//  - attn_loop h-split x2 (z=8): LDS 26.6KB -> 6 blocks/CU resident, grid
//    1024 -> 16 waves/CU (2x occ). Same total LDS/VALU work. Halves write
//    disjoint partials pA = Swd-2accA, pB = -2accB.
//  - attn_epi: flat separate kernel, float4-coalesced pA/pB/mask/out,
//    4 sites/thread, x4-interleaved threefry, no LDS, high occupancy.
// Math per site bit-identical (one extra add-rounding in d).
// ---------------------------------------------------------------------------

#define BB 4
#define LLEN 512
#define DD 256
#define HH 128

#define TWO_LOG2E 2.8853900817779268f   // 2*log2(e)
#define LOG2E_100 144.26950408889634f   // 100*log2(e)

#define NSITES (BB * LLEN * LLEN)       // 1048576

__device__ __forceinline__ uint32_t rotl32(uint32_t v, int r) {
  return __builtin_amdgcn_alignbit(v, v, 32 - r);
}

// ---- 4 independent threefry-2x32 chains, interleaved round-by-round ----
__device__ __forceinline__ void tf4_round(uint32_t x0[4], uint32_t x1[4],
                                          const int r) {
  #pragma unroll
  for (int i = 0; i < 4; ++i) {
    x0[i] += x1[i];
    x1[i] = rotl32(x1[i], r);
    x1[i] ^= x0[i];
  }
}
__device__ __forceinline__ void tf4_key(uint32_t x0[4], uint32_t x1[4],
                                        const uint32_t a, const uint32_t b) {
  #pragma unroll
  for (int i = 0; i < 4; ++i) { x0[i] += a; x1[i] += b; }
}

// counter (0, c[i]), key (0,42); returns o0^o1 per chain
__device__ __forceinline__ void tf2x32_x4(const uint32_t c[4], uint32_t o[4]) {
  const uint32_t k0 = 0u;
  const uint32_t k1 = 42u;
  const uint32_t k2 = 0x1BD11BDAu ^ k0 ^ k1;   // 0x1BD11BF0

  uint32_t x0[4], x1[4];
  #pragma unroll
  for (int i = 0; i < 4; ++i) { x0[i] = k0; x1[i] = c[i] + k1; }

  tf4_round(x0, x1, 13); tf4_round(x0, x1, 15);
  tf4_round(x0, x1, 26); tf4_round(x0, x1, 6);
  tf4_key(x0, x1, k1, k2 + 1u);
  tf4_round(x0, x1, 17); tf4_round(x0, x1, 29);
  tf4_round(x0, x1, 16); tf4_round(x0, x1, 24);
  tf4_key(x0, x1, k2, k0 + 2u);
  tf4_round(x0, x1, 13); tf4_round(x0, x1, 15);
  tf4_round(x0, x1, 26); tf4_round(x0, x1, 6);
  tf4_key(x0, x1, k0, k1 + 3u);
  tf4_round(x0, x1, 17); tf4_round(x0, x1, 29);
  tf4_round(x0, x1, 16); tf4_round(x0, x1, 24);
  tf4_key(x0, x1, k1, k2 + 4u);
  tf4_round(x0, x1, 13); tf4_round(x0, x1, 15);
  tf4_round(x0, x1, 26); tf4_round(x0, x1, 6);
  tf4_key(x0, x1, k2, k0 + 5u);

  #pragma unroll
  for (int i = 0; i < 4; ++i) o[i] = x0[i] ^ x1[i];
}

__device__ __forceinline__ float u01_from_bits(uint32_t bits) {
  const float f = __uint_as_float((bits >> 9) | 0x3F800000u) - 1.0f;
  return fmaxf(f, 1.17549435e-38f);
}

// ---------------------------------------------------------------------------
// Kernel A: projections -> EQ = exp2(c * q.Wq^T), EK = exp2(c * k.Wk^T).
// (R8-R16 verbatim)
// ---------------------------------------------------------------------------
__global__ __launch_bounds__(128) void proj_kernel(
    const float* __restrict__ queries, const float* __restrict__ keys,
    const float* __restrict__ Wq, const float* __restrict__ Wk,
    float* __restrict__ EQ, float* __restrict__ EK) {
  const int blk = blockIdx.x;
  const bool isK = blk >= 512;
  const int rb = (isK ? blk - 512 : blk) * 4;
  const float* __restrict__ in = isK ? keys : queries;
  const float* __restrict__ W  = isK ? Wk : Wq;
  float* __restrict__ outp     = isK ? EK : EQ;

  __shared__ float rows[4][DD];
  const float4* in4 = reinterpret_cast<const float4*>(in + (size_t)rb * DD);
  float4* rows4 = reinterpret_cast<float4*>(&rows[0][0]);
  #pragma unroll
  for (int t = threadIdx.x; t < 4 * DD / 4; t += 128) rows4[t] = in4[t];
  __syncthreads();

  const int h = threadIdx.x;
  const float4* W4 = reinterpret_cast<const float4*>(W + (size_t)h * DD);
  float a0 = 0.f, a1 = 0.f, a2 = 0.f, a3 = 0.f;
  #pragma unroll 8
  for (int d4 = 0; d4 < DD / 4; ++d4) {
    const float4 w = W4[d4];
    const int d = d4 * 4;
    a0 = fmaf(w.x, rows[0][d], fmaf(w.y, rows[0][d+1], fmaf(w.z, rows[0][d+2], fmaf(w.w, rows[0][d+3], a0))));
    a1 = fmaf(w.x, rows[1][d], fmaf(w.y, rows[1][d+1], fmaf(w.z, rows[1][d+2], fmaf(w.w, rows[1][d+3], a1))));
    a2 = fmaf(w.x, rows[2][d], fmaf(w.y, rows[2][d+1], fmaf(w.z, rows[2][d+2], fmaf(w.w, rows[2][d+3], a2))));
    a3 = fmaf(w.x, rows[3][d], fmaf(w.y, rows[3][d+1], fmaf(w.z, rows[3][d+2], fmaf(w.w, rows[3][d+3], a3))));
  }
  float* orow = outp + (size_t)rb * HH + h;
  orow[0 * HH] = __builtin_amdgcn_exp2f(a0 * TWO_LOG2E);
  orow[1 * HH] = __builtin_amdgcn_exp2f(a1 * TWO_LOG2E);
  orow[2 * HH] = __builtin_amdgcn_exp2f(a2 * TWO_LOG2E);
  orow[3 * HH] = __builtin_amdgcn_exp2f(a3 * TWO_LOG2E);
}

// ---------------------------------------------------------------------------
// Shared-rcp 4-group site macro (identical to R9-R16, passing)
// ---------------------------------------------------------------------------
#define GRP(accv, qv, kv, wd) {                                       \
    float4 A_;                                                        \
    A_.x = fmaf((qv).x, (kv).x, 1.0f);                                \
    A_.y = fmaf((qv).y, (kv).y, 1.0f);                                \
    A_.z = fmaf((qv).z, (kv).z, 1.0f);                                \
    A_.w = fmaf((qv).w, (kv).w, 1.0f);                                \
    const float p01_ = A_.x * A_.y;                                   \
    const float p23_ = A_.z * A_.w;                                   \
    const float n01_ = fmaf((wd).x, A_.y, (wd).y * A_.x);             \
    const float n23_ = fmaf((wd).z, A_.w, (wd).w * A_.z);             \
    const float num_ = fmaf(n01_, p23_, n23_ * p01_);                 \
    const float rc_  = __builtin_amdgcn_rcpf(p01_ * p23_);            \
    (accv) = fmaf(num_, rc_, (accv)); }

// ---------------------------------------------------------------------------
// attn_loop: 32i x 64j tile, h-SPLIT x2. grid (16,8,8): b=z>>1, half=z&1.
// Each block sums 16 h4-chunks (h in [half*64, half*64+64)).
// LDS 26.6KB -> 6 blocks/CU resident. Writes partials (no mask, no gumbel):
//   half 0: pA = Swd - 2*acc ;  half 1: pB = -2*acc.
// ---------------------------------------------------------------------------
__global__ __launch_bounds__(256) void attn_loop(
    const float* __restrict__ EQ, const float* __restrict__ EK,
    const float* __restrict__ Wv, float* __restrict__ pbuf) {
  __shared__ float4 QL[32][17];   // 8.5 KB
  __shared__ float4 KL[64][17];   // 17.0 KB
  __shared__ float4 wdL[32];      // 0.5 KB

  const int bi = blockIdx.x, bj = blockIdx.y;
  const int b = blockIdx.z >> 1, half = blockIdx.z & 1;
  const int i0 = bi * 32, j0 = bj * 64;
  const int h4b = half * 16;

  const float4* Q4 = reinterpret_cast<const float4*>(EQ) + ((size_t)b * LLEN + i0) * (HH / 4);
  const float4* K4 = reinterpret_cast<const float4*>(EK) + ((size_t)b * LLEN + j0) * (HH / 4);
  // stage 32x16 (Q) + 64x16 (K) float4 chunks of this h-half
  for (int t = threadIdx.x; t < 512 + 1024; t += 256) {
    if (t < 512) {
      const int row = t >> 4, hh = t & 15;
      QL[row][hh] = Q4[row * (HH / 4) + h4b + hh];
    } else {
      const int u = t - 512;
      const int row = u >> 4, hh = u & 15;
      KL[row][hh] = K4[row * (HH / 4) + h4b + hh];
    }
  }
  if (threadIdx.x < 32) {
    const float4 w0 = reinterpret_cast<const float4*>(Wv)[threadIdx.x];
    const float4 w1 = reinterpret_cast<const float4*>(Wv)[32 + threadIdx.x];
    float4 wd; wd.x = w0.x - w1.x; wd.y = w0.y - w1.y;
    wd.z = w0.z - w1.z; wd.w = w0.w - w1.w;
    wdL[threadIdx.x] = wd;
  }
  __syncthreads();

  const int jj = threadIdx.x & 31;   // cols j0+jj, j0+jj+32
  const int ib = threadIdx.x >> 5;   // rows ib, ib+8, ib+16, ib+24

  // full Swd (all 32 chunks), folded only by half 0
  float Swd = 0.f;
  #pragma unroll
  for (int t = 0; t < 32; ++t) {
    const float4 wd = wdL[t];
    Swd += (wd.x + wd.y) + (wd.z + wd.w);
  }
  const float base = half ? 0.0f : Swd;

  float acc[4][2] = {{0.f,0.f},{0.f,0.f},{0.f,0.f},{0.f,0.f}};

  #pragma unroll 4
  for (int h4 = 0; h4 < 16; ++h4) {
    const float4 kv0 = KL[jj][h4];
    const float4 kv1 = KL[jj + 32][h4];
    const float4 wd  = wdL[h4b + h4];
    const float4 qv0 = QL[ib][h4];
    const float4 qv1 = QL[ib + 8][h4];
    const float4 qv2 = QL[ib + 16][h4];
    const float4 qv3 = QL[ib + 24][h4];
    GRP(acc[0][0], qv0, kv0, wd) GRP(acc[0][1], qv0, kv1, wd)
    GRP(acc[1][0], qv1, kv0, wd) GRP(acc[1][1], qv1, kv1, wd)
    GRP(acc[2][0], qv2, kv0, wd) GRP(acc[2][1], qv2, kv1, wd)
    GRP(acc[3][0], qv3, kv0, wd) GRP(acc[3][1], qv3, kv1, wd)
  }

  float* __restrict__ pb = pbuf + (size_t)half * NSITES;
  const uint32_t row0 = (uint32_t)b * LLEN + i0 + ib;
  const uint32_t col0 = j0 + jj;
  #pragma unroll
  for (int r = 0; r < 4; ++r) {
    #pragma unroll
    for (int c = 0; c < 2; ++c) {
      const uint32_t idx = (row0 + 8u * r) * LLEN + col0 + 32u * c;
      pb[idx] = fmaf(-2.0f, acc[r][c], base);
    }
  }
}

// ---------------------------------------------------------------------------
// attn_epi: flat, LDS-free, high-occupancy. 4 consecutive sites/thread,
// float4-coalesced everything. d = pA + pB; threefry x4-interleaved.
// grid 1024 x 256 thr = 262144 threads x 4 sites = 1048576.
// ---------------------------------------------------------------------------
__global__ __launch_bounds__(256) void attn_epi(
    const float* __restrict__ pA, const float* __restrict__ pB,
    const int* __restrict__ mask, float* __restrict__ out) {
  const uint32_t t4 = (uint32_t)blockIdx.x * 256u + threadIdx.x;
  const uint32_t s0 = t4 * 4u;   // first of 4 consecutive sites

  const float4 a = reinterpret_cast<const float4*>(pA)[t4];
  const float4 bv = reinterpret_cast<const float4*>(pB)[t4];
  const int4  m  = reinterpret_cast<const int4*>(mask)[t4];

  float dv[4];
  dv[0] = a.x + bv.x; dv[1] = a.y + bv.y;
  dv[2] = a.z + bv.z; dv[3] = a.w + bv.w;

  uint32_t c0[4], c1[4];
  #pragma unroll
  for (int k = 0; k < 4; ++k) {
    c0[k] = (s0 + (uint32_t)k) * 2u;
    c1[k] = (s0 + (uint32_t)k) * 2u + 1u;
  }
  uint32_t b0[4], b1[4];
  tf2x32_x4(c0, b0);
  tf2x32_x4(c1, b1);

  float o[4];
  #pragma unroll
  for (int k = 0; k < 4; ++k) {
    const float l0 = __log2f(u01_from_bits(b0[k]));
    const float l1 = __log2f(u01_from_bits(b1[k]));
    const float rl = l1 * __builtin_amdgcn_rcpf(l0);
    const float g_ = 100.0f * __log2f(rl);
    const float t_ = fmaf(dv[k], LOG2E_100, g_);
    o[k] = __builtin_amdgcn_rcpf(1.0f + __builtin_amdgcn_exp2f(-t_));
  }

  float4 res;
  res.x = (m.x >= 2) ? o[0] : 1.0f;
  res.y = (m.y >= 2) ? o[1] : 1.0f;
  res.z = (m.z >= 2) ? o[2] : 1.0f;
  res.w = (m.w >= 2) ? o[3] : 1.0f;
  reinterpret_cast<float4*>(out)[t4] = res;
}

extern "C" void kernel_launch(void* const* d_in, const int* in_sizes, int n_in,
                              void* d_out, int out_size, void* d_ws, size_t ws_size,
                              hipStream_t stream) {
  const float* queries = (const float*)d_in[0];
  const float* keys    = (const float*)d_in[1];
  const int*   mask    = (const int*)d_in[2];
  const float* Wq      = (const float*)d_in[3];
  const float* Wk      = (const float*)d_in[4];
  const float* Wv      = (const float*)d_in[5];
  float* out = (float*)d_out;

  float* EQ   = (float*)d_ws;                  // 1 MB
  float* EK   = EQ + (size_t)BB * LLEN * HH;   // 1 MB
  float* pbuf = EK + (size_t)BB * LLEN * HH;   // 2 x 4.19 MB partials

  proj_kernel<<<dim3(1024), dim3(128), 0, stream>>>(
      queries, keys, Wq, Wk, EQ, EK);
  attn_loop<<<dim3(LLEN / 32, LLEN / 64, 2 * BB), dim3(256), 0, stream>>>(
      EQ, EK, Wv, pbuf);
  attn_epi<<<dim3(NSITES / 4 / 256), dim3(256), 0, stream>>>(
      pbuf, pbuf + NSITES, mask, out);
}

// Round 18
// 46.903 us; speedup vs baseline: 1.0142x; 1.0142x over previous
//
#include <hip/hip_runtime.h>
#include <stdint.h>

// ---------------------------------------------------------------------------
// AdditiveAttention (Bahdanau) + gumbel-softmax(tau=0.01), channel 0.
//
// out[b,i,j] = (mask==1) ? 1.0 : sigmoid((d + g0 - g1)*100),
//   d = sum_h tanh(q+k)*(w0-w1);  g bit-exact jax threefry (verified R3-R17).
//
// R18 = R13 (best, 42.1us) + ONE change: 16-wide shared-rcp rational tree
// in the attn loop. Hypothesis (fits R5-R17 ledger): wave64 trans ops
// block SIMD issue ~48-64cy, so the loop's 256 rcp/thread cost ~13us.
// Two-level tree: chunk (4h): nc/pc (13 VALU); pair (8h): N8=na*pb+nb*pa,
// D8=pa*pb (3); merge (16h) + 1 rcp + acc fma. 1 rcp per 16h per output
// (64/thread, was 256), VALU-neutral. D16=prod(1+x) overflow needs 11
// sigma -> negligible; D16>=1 so no underflow.
// prep (proj+dense gumbel, heterogeneous grid) and light epi: R13 verbatim.
// ---------------------------------------------------------------------------

#define BB 4
#define LLEN 512
#define DD 256
#define HH 128

#define TWO_LOG2E 2.8853900817779268f   // 2*log2(e)
#define LOG2E_100 144.26950408889634f   // 100*log2(e)

#define NSITES (BB * LLEN * LLEN)       // 1048576
#define GUMBEL_THREADS (NSITES / 2)     // 524288 threads, 2 sites each

__device__ __forceinline__ uint32_t rotl32(uint32_t v, int r) {
  return __builtin_amdgcn_alignbit(v, v, 32 - r);
}

// Threefry-2x32, key = (0, 42)
__device__ __forceinline__ void tf2x32(uint32_t x0, uint32_t x1,
                                       uint32_t& o0, uint32_t& o1) {
  const uint32_t k0 = 0u;
  const uint32_t k1 = 42u;
  const uint32_t k2 = 0x1BD11BDAu ^ k0 ^ k1;

  x0 += k0; x1 += k1;
#define TFR(r) { x0 += x1; x1 = rotl32(x1, (r)); x1 ^= x0; }
  TFR(13) TFR(15) TFR(26) TFR(6)
  x0 += k1; x1 += k2 + 1u;
  TFR(17) TFR(29) TFR(16) TFR(24)
  x0 += k2; x1 += k0 + 2u;
  TFR(13) TFR(15) TFR(26) TFR(6)
  x0 += k0; x1 += k1 + 3u;
  TFR(17) TFR(29) TFR(16) TFR(24)
  x0 += k1; x1 += k2 + 4u;
  TFR(13) TFR(15) TFR(26) TFR(6)
  x0 += k2; x1 += k0 + 5u;
#undef TFR
  o0 = x0; o1 = x1;
}

// u in (0,1) from jax partitionable random_bits (counter (0,flat), o0^o1)
__device__ __forceinline__ float jax_u01(uint32_t flat) {
  uint32_t o0, o1;
  tf2x32(0u, flat, o0, o1);
  const uint32_t bits = o0 ^ o1;
  const float f = __uint_as_float((bits >> 9) | 0x3F800000u) - 1.0f;
  return fmaxf(f, 1.17549435e-38f);
}

// ---------------------------------------------------------------------------
// prep_kernel: heterogeneous grid (R13 verbatim).
//   blk < 512      : Q proj;  512 <= blk < 1024: K proj
//   blk >= 1024    : dense gumbel G[s] = 100*(log2 l1 - log2 l0)
// ---------------------------------------------------------------------------
__global__ __launch_bounds__(128) void prep_kernel(
    const float* __restrict__ queries, const float* __restrict__ keys,
    const float* __restrict__ Wq, const float* __restrict__ Wk,
    float* __restrict__ EQ, float* __restrict__ EK, float* __restrict__ G) {
  const int blk = blockIdx.x;

  if (blk >= 1024) {
    const uint32_t base = (uint32_t)(blk - 1024) * 128u + threadIdx.x;
    #pragma unroll
    for (int rep = 0; rep < 2; ++rep) {
      const uint32_t s = base + (uint32_t)rep * GUMBEL_THREADS;
      const float l0 = __log2f(jax_u01(s * 2u));
      const float l1 = __log2f(jax_u01(s * 2u + 1u));
      const float rl = l1 * __builtin_amdgcn_rcpf(l0);
      G[s] = 100.0f * __log2f(rl);
    }
    return;
  }

  const bool isK = blk >= 512;
  const int rb = (isK ? blk - 512 : blk) * 4;
  const float* __restrict__ in = isK ? keys : queries;
  const float* __restrict__ W  = isK ? Wk : Wq;
  float* __restrict__ outp     = isK ? EK : EQ;

  __shared__ float rows[4][DD];
  const float4* in4 = reinterpret_cast<const float4*>(in + (size_t)rb * DD);
  float4* rows4 = reinterpret_cast<float4*>(&rows[0][0]);
  #pragma unroll
  for (int t = threadIdx.x; t < 4 * DD / 4; t += 128) rows4[t] = in4[t];
  __syncthreads();

  const int h = threadIdx.x;
  const float4* W4 = reinterpret_cast<const float4*>(W + (size_t)h * DD);
  float a0 = 0.f, a1 = 0.f, a2 = 0.f, a3 = 0.f;
  #pragma unroll 8
  for (int d4 = 0; d4 < DD / 4; ++d4) {
    const float4 w = W4[d4];
    const int d = d4 * 4;
    a0 = fmaf(w.x, rows[0][d], fmaf(w.y, rows[0][d+1], fmaf(w.z, rows[0][d+2], fmaf(w.w, rows[0][d+3], a0))));
    a1 = fmaf(w.x, rows[1][d], fmaf(w.y, rows[1][d+1], fmaf(w.z, rows[1][d+2], fmaf(w.w, rows[1][d+3], a1))));
    a2 = fmaf(w.x, rows[2][d], fmaf(w.y, rows[2][d+1], fmaf(w.z, rows[2][d+2], fmaf(w.w, rows[2][d+3], a2))));
    a3 = fmaf(w.x, rows[3][d], fmaf(w.y, rows[3][d+1], fmaf(w.z, rows[3][d+2], fmaf(w.w, rows[3][d+3], a3))));
  }
  float* orow = outp + (size_t)rb * HH + h;
  orow[0 * HH] = __builtin_amdgcn_exp2f(a0 * TWO_LOG2E);
  orow[1 * HH] = __builtin_amdgcn_exp2f(a1 * TWO_LOG2E);
  orow[2 * HH] = __builtin_amdgcn_exp2f(a2 * TWO_LOG2E);
  orow[3 * HH] = __builtin_amdgcn_exp2f(a3 * TWO_LOG2E);
}

// ---------------------------------------------------------------------------
// 16-wide rational tree macros.
// CHUNK: 4 h-elements -> (nc, pc) with sum wd/A = nc/pc.   13 VALU, 0 trans
// STAGE: two chunks -> 8-wide (N8, D8).                    +3 VALU
// FIN:   two 8-wides -> 16-wide, 1 rcp, acc fma.           +5 VALU, 1 trans
// ---------------------------------------------------------------------------
#define CHUNK(nc, pc, qv, kv, wd) {                        \
    float4 A_;                                             \
    A_.x = fmaf((qv).x, (kv).x, 1.0f);                     \
    A_.y = fmaf((qv).y, (kv).y, 1.0f);                     \
    A_.z = fmaf((qv).z, (kv).z, 1.0f);                     \
    A_.w = fmaf((qv).w, (kv).w, 1.0f);                     \
    const float p01_ = A_.x * A_.y;                        \
    const float p23_ = A_.z * A_.w;                        \
    const float n01_ = fmaf((wd).x, A_.y, (wd).y * A_.x);  \
    const float n23_ = fmaf((wd).z, A_.w, (wd).w * A_.z);  \
    (nc) = fmaf(n01_, p23_, n23_ * p01_);                  \
    (pc) = p01_ * p23_; }

#define STAGE(N8v, D8v, qa, ka, wa, qb, kb, wb) {          \
    float na_, pa_, nb_, pb_;                              \
    CHUNK(na_, pa_, qa, ka, wa)                            \
    CHUNK(nb_, pb_, qb, kb, wb)                            \
    (N8v) = fmaf(na_, pb_, nb_ * pa_);                     \
    (D8v) = pa_ * pb_; }

#define FIN(accv, N8v, D8v, qa, ka, wa, qb, kb, wb) {      \
    float Nb_, Db_;                                        \
    STAGE(Nb_, Db_, qa, ka, wa, qb, kb, wb)                \
    const float Nt_ = fmaf((N8v), Db_, Nb_ * (D8v));       \
    const float Dt_ = (D8v) * Db_;                         \
    const float rc_ = __builtin_amdgcn_rcpf(Dt_);          \
    (accv) = fmaf(Nt_, rc_, (accv)); }

// ---------------------------------------------------------------------------
// attn_kernel: 32i x 64j tile (grid 16x8x4), 256 thr, 8 outputs/thread.
// Inner loop: 8 groups of 16 h, ONE rcp per group per output.
// Light fused epilogue reading precomputed G (R13 verbatim).
// ---------------------------------------------------------------------------
__global__ __launch_bounds__(256) void attn_kernel(
    const float* __restrict__ EQ, const float* __restrict__ EK,
    const int* __restrict__ mask, const float* __restrict__ Wv,
    const float* __restrict__ G, float* __restrict__ out) {
  __shared__ float4 QL[32][33];
  __shared__ float4 KL[64][33];
  __shared__ float4 wdL[32];

  const int bi = blockIdx.x, bj = blockIdx.y, b = blockIdx.z;
  const int i0 = bi * 32, j0 = bj * 64;

  const float4* Q4 = reinterpret_cast<const float4*>(EQ) + ((size_t)b * LLEN + i0) * (HH / 4);
  const float4* K4 = reinterpret_cast<const float4*>(EK) + ((size_t)b * LLEN + j0) * (HH / 4);
  for (int t = threadIdx.x; t < 1024 + 2048; t += 256) {
    if (t < 1024) {
      QL[t >> 5][t & 31] = Q4[t];
    } else {
      const int u = t - 1024;
      KL[u >> 5][u & 31] = K4[u];
    }
  }
  if (threadIdx.x < 32) {
    const float4 w0 = reinterpret_cast<const float4*>(Wv)[threadIdx.x];
    const float4 w1 = reinterpret_cast<const float4*>(Wv)[32 + threadIdx.x];
    float4 wd; wd.x = w0.x - w1.x; wd.y = w0.y - w1.y;
    wd.z = w0.z - w1.z; wd.w = w0.w - w1.w;
    wdL[threadIdx.x] = wd;
  }
  __syncthreads();

  const int jj = threadIdx.x & 31;   // cols j0+jj, j0+jj+32
  const int ib = threadIdx.x >> 5;   // rows ib, ib+8, ib+16, ib+24

  // prefetch mask + G (16 coalesced loads, hidden under the loop)
  const uint32_t row0 = (uint32_t)b * LLEN + i0 + ib;
  const uint32_t col0 = j0 + jj;
  int   mreg[4][2];
  float greg[4][2];
  #pragma unroll
  for (int r = 0; r < 4; ++r)
    #pragma unroll
    for (int c = 0; c < 2; ++c) {
      const uint32_t idx = (row0 + 8u * r) * LLEN + col0 + 32u * c;
      mreg[r][c] = mask[idx];
      greg[r][c] = G[idx];
    }

  float Swd = 0.f;
  #pragma unroll
  for (int t = 0; t < 32; ++t) {
    const float4 wd = wdL[t];
    Swd += (wd.x + wd.y) + (wd.z + wd.w);
  }

  float acc[4][2] = {{0.f,0.f},{0.f,0.f},{0.f,0.f},{0.f,0.f}};

  for (int g = 0; g < 8; ++g) {       // 16 h per group
    const int h4 = g * 4;
    float N8[4][2], D8[4][2];

    // ---- chunks 0,1 of the group -> 8-wide partials
    {
      const float4 ka0 = KL[jj][h4],      ka1 = KL[jj + 32][h4];
      const float4 kb0 = KL[jj][h4 + 1],  kb1 = KL[jj + 32][h4 + 1];
      const float4 wa  = wdL[h4], wb = wdL[h4 + 1];
      const float4 qa0 = QL[ib][h4],      qb0 = QL[ib][h4 + 1];
      const float4 qa1 = QL[ib + 8][h4],  qb1 = QL[ib + 8][h4 + 1];
      const float4 qa2 = QL[ib + 16][h4], qb2 = QL[ib + 16][h4 + 1];
      const float4 qa3 = QL[ib + 24][h4], qb3 = QL[ib + 24][h4 + 1];
      STAGE(N8[0][0], D8[0][0], qa0, ka0, wa, qb0, kb0, wb)
      STAGE(N8[0][1], D8[0][1], qa0, ka1, wa, qb0, kb1, wb)
      STAGE(N8[1][0], D8[1][0], qa1, ka0, wa, qb1, kb0, wb)
      STAGE(N8[1][1], D8[1][1], qa1, ka1, wa, qb1, kb1, wb)
      STAGE(N8[2][0], D8[2][0], qa2, ka0, wa, qb2, kb0, wb)
      STAGE(N8[2][1], D8[2][1], qa2, ka1, wa, qb2, kb1, wb)
      STAGE(N8[3][0], D8[3][0], qa3, ka0, wa, qb3, kb0, wb)
      STAGE(N8[3][1], D8[3][1], qa3, ka1, wa, qb3, kb1, wb)
    }
    // ---- chunks 2,3 -> merge to 16-wide, single rcp, accumulate
    {
      const float4 ka0 = KL[jj][h4 + 2],      ka1 = KL[jj + 32][h4 + 2];
      const float4 kb0 = KL[jj][h4 + 3],      kb1 = KL[jj + 32][h4 + 3];
      const float4 wa  = wdL[h4 + 2], wb = wdL[h4 + 3];
      const float4 qa0 = QL[ib][h4 + 2],      qb0 = QL[ib][h4 + 3];
      const float4 qa1 = QL[ib + 8][h4 + 2],  qb1 = QL[ib + 8][h4 + 3];
      const float4 qa2 = QL[ib + 16][h4 + 2], qb2 = QL[ib + 16][h4 + 3];
      const float4 qa3 = QL[ib + 24][h4 + 2], qb3 = QL[ib + 24][h4 + 3];
      FIN(acc[0][0], N8[0][0], D8[0][0], qa0, ka0, wa, qb0, kb0, wb)
      FIN(acc[0][1], N8[0][1], D8[0][1], qa0, ka1, wa, qb0, kb1, wb)
      FIN(acc[1][0], N8[1][0], D8[1][0], qa1, ka0, wa, qb1, kb0, wb)
      FIN(acc[1][1], N8[1][1], D8[1][1], qa1, ka1, wa, qb1, kb1, wb)
      FIN(acc[2][0], N8[2][0], D8[2][0], qa2, ka0, wa, qb2, kb0, wb)
      FIN(acc[2][1], N8[2][1], D8[2][1], qa2, ka1, wa, qb2, kb1, wb)
      FIN(acc[3][0], N8[3][0], D8[3][0], qa3, ka0, wa, qb3, kb0, wb)
      FIN(acc[3][1], N8[3][1], D8[3][1], qa3, ka1, wa, qb3, kb1, wb)
    }
  }

  // light epilogue: coalesced writes, branchless select (R13 verbatim)
  #pragma unroll
  for (int r = 0; r < 4; ++r) {
    #pragma unroll
    for (int c = 0; c < 2; ++c) {
      const uint32_t idx = (row0 + 8u * r) * LLEN + col0 + 32u * c;
      const float d_ = fmaf(-2.0f, acc[r][c], Swd);
      const float t_ = fmaf(d_, LOG2E_100, greg[r][c]);
      const float o_ = __builtin_amdgcn_rcpf(1.0f + __builtin_amdgcn_exp2f(-t_));
      out[idx] = (mreg[r][c] >= 2) ? o_ : 1.0f;
    }
  }
}

extern "C" void kernel_launch(void* const* d_in, const int* in_sizes, int n_in,
                              void* d_out, int out_size, void* d_ws, size_t ws_size,
                              hipStream_t stream) {
  const float* queries = (const float*)d_in[0];
  const float* keys    = (const float*)d_in[1];
  const int*   mask    = (const int*)d_in[2];
  const float* Wq      = (const float*)d_in[3];
  const float* Wk      = (const float*)d_in[4];
  const float* Wv      = (const float*)d_in[5];
  float* out = (float*)d_out;

  float* EQ = (float*)d_ws;                 // 1 MB
  float* EK = EQ + (size_t)BB * LLEN * HH;  // 1 MB
  float* G  = EK + (size_t)BB * LLEN * HH;  // 4.19 MB

  prep_kernel<<<dim3(1024 + GUMBEL_THREADS / 128), dim3(128), 0, stream>>>(
      queries, keys, Wq, Wk, EQ, EK, G);
  attn_kernel<<<dim3(LLEN / 32, LLEN / 64, BB), dim3(256), 0, stream>>>(
      EQ, EK, mask, Wv, G, out);
}